// Round 3
// baseline (219.900 us; speedup 1.0000x reference)
//
#include <hip/hip_runtime.h>

#define B_DIM 8
#define N_DIM 2048
#define F_DIM 128

typedef __attribute__((ext_vector_type(8))) __bf16 bf16x8;
typedef __attribute__((ext_vector_type(4))) float f32x4;

__device__ __forceinline__ __bf16 f2bf(float f) {
  unsigned u = __builtin_bit_cast(unsigned, f);
  u += 0x7FFFu + ((u >> 16) & 1u);                 // round-to-nearest-even
  unsigned short s = (unsigned short)(u >> 16);
  return __builtin_bit_cast(__bf16, s);
}

// Kernel 1: xT[b][f][n] = bf16(x[b][n][f])  — pure transpose+convert.
// Reassociation (adj@x)@W means the big kernel's B-operand is x itself; this
// 12 MB streaming pass replaces the old x@W producer GEMM. Reads are
// coalesced 256B row segments (lanes vary f); writes are 16B/lane at 4 KB
// stride (4 MB logical -> a few MB effective; ~3 us).
__global__ __launch_bounds__(256) void gcn_xt(const float* __restrict__ x,
                                              __bf16* __restrict__ xT) {
  const int tid = threadIdx.x;
  const int b = blockIdx.x >> 5;
  const int n0 = (blockIdx.x & 31) << 6;   // 64 nodes per WG
  const int f = tid & 127;
  const int ng = tid >> 7;                 // 0 or 1
  const float* xb = x + (size_t)b * N_DIM * F_DIM;
  __bf16* xo = xT + ((size_t)b * F_DIM + f) * N_DIM;
#pragma unroll
  for (int g = 0; g < 2; ++g) {
    const int n16 = n0 + ng * 32 + g * 16;
    bf16x8 v0, v1;
#pragma unroll
    for (int e = 0; e < 8; ++e)
      v0[e] = f2bf(xb[(size_t)(n16 + e) * F_DIM + f]);
#pragma unroll
    for (int e = 0; e < 8; ++e)
      v1[e] = f2bf(xb[(size_t)(n16 + 8 + e) * F_DIM + f]);
    *reinterpret_cast<bf16x8*>(&xo[n16]) = v0;
    *reinterpret_cast<bf16x8*>(&xo[n16 + 8]) = v1;
  }
}

// Fused kernel: y[m][f] = sum_k adj[b][m][k] * x[b][k][f]  (k-loop, 32 iters)
// then        out[m][j] = sum_f y[m][f] * W[f][j] + bias[j] (epilogue MFMA)
// 32(M) x 128(F) tile per 256-thr WG, grid 512 = 2 blocks/CU. b = blockIdx&7
// pins each batch's xT (512 KB) to one XCD L2; adj reads nontemporal.
// xT staged via global_load_lds width-16, triple-buffered, oct-XOR swizzle on
// the global source + on ds_read (2-way/free banks). adj prefetch 2 deep in
// two static register banks (loop unrolled x2 for static parity). Counted
// vmcnt(6): queue = adj(t+1)x2 + sup(t+1)x4 + adj(t+2)x2 + sup(t+2)x4 = 12,
// keep 6 -> exactly tile t+1 retired; loads stay in flight across barriers.
// Epilogue reuses As as y_lds[32][136] and Bs as WT[128][136] (pad-136 ->
// ~2-way banks on b128 reads).
__global__ __launch_bounds__(256, 2) void gcn_fused(const float* __restrict__ adj,
                                                    const __bf16* __restrict__ xT,
                                                    const float* __restrict__ W,
                                                    const float* __restrict__ bias,
                                                    float* __restrict__ out) {
  __shared__ __bf16 As[2][32 * 72];    // adj tile [m][k] bf16; epilogue: y_lds
  __shared__ __bf16 Bs[3][128 * 64];   // xT tile, oct-swizzled; epilogue: WT
  const int tid = threadIdx.x;
  const int lane = tid & 63;
  const int wave = tid >> 6;           // 0..3
  const int b = blockIdx.x & 7;
  const int m0 = (blockIdx.x >> 3) << 5;

  const int nsub = wave << 5;          // wave's 32-wide f (and j) slice

  const float* adjb = adj + ((size_t)b * N_DIM + m0) * N_DIM;
  const __bf16* sb = xT + (size_t)b * F_DIM * N_DIM;

  const int arow = tid >> 3;           // adj staging: 8 thr/row, 8 f32 each
  const int acol = (tid & 7) << 3;

  f32x4 paA[2], paB[2];                // two static prefetch banks (even/odd tiles)

  auto issue_adj = [&](int kk, f32x4* pa) {
    const f32x4* ap = reinterpret_cast<const f32x4*>(adjb + (size_t)arow * N_DIM + kk + acol);
    pa[0] = __builtin_nontemporal_load(ap);
    pa[1] = __builtin_nontemporal_load(ap + 1);
  };
  auto issue_sup = [&](int kk, int buf) {
    // chunk L = i*256+tid -> row n = L>>3, slot L&7; source oct = slot^(n&7)
#pragma unroll
    for (int i = 0; i < 4; ++i) {
      const int L = i * 256 + tid;
      const int n = L >> 3;
      const int s = (L & 7) ^ (n & 7);
      const __bf16* src = sb + (size_t)n * N_DIM + kk + (s << 3);
      __bf16* dst = &Bs[buf][i * 2048 + ((tid & 192) << 3)];   // wave-uniform base
      __builtin_amdgcn_global_load_lds(
          (const __attribute__((address_space(1))) void*)src,
          (__attribute__((address_space(3))) void*)dst, 16, 0, 0);
    }
  };
  auto store_adj = [&](f32x4* pa, int buf) {
    bf16x8 v;
    v[0] = f2bf(pa[0].x); v[1] = f2bf(pa[0].y); v[2] = f2bf(pa[0].z); v[3] = f2bf(pa[0].w);
    v[4] = f2bf(pa[1].x); v[5] = f2bf(pa[1].y); v[6] = f2bf(pa[1].z); v[7] = f2bf(pa[1].w);
    *reinterpret_cast<bf16x8*>(&As[buf][arow * 72 + acol]) = v;
  };

  f32x4 acc[2][2] = {};
  const int q = lane >> 4;
  const int q8 = q << 3;
  const int c = lane & 15;
  const int c7 = c & 7;

  // Prologue: tiles 0 and 1 fully issued; wait only tile 0 (keep 6 in flight).
  issue_adj(0, paA);
  issue_sup(0, 0);
  issue_adj(64, paB);
  issue_sup(64, 1);
  asm volatile("s_waitcnt vmcnt(6)" ::: "memory");
  __builtin_amdgcn_sched_barrier(0);
  store_adj(paA, 0);
  asm volatile("s_waitcnt lgkmcnt(0)" ::: "memory");
  __builtin_amdgcn_sched_barrier(0);
  __builtin_amdgcn_s_barrier();

  auto body = [&](int t, f32x4* pa_i, f32x4* pa_s) {
    const int cur = t % 3;
    if (t <= 29) {                      // issue tile t+2 before compute
      issue_adj((t + 2) * 64, pa_i);
      issue_sup((t + 2) * 64, (t + 2) % 3);
    }
    __builtin_amdgcn_sched_barrier(0);  // pin issues ahead of the MFMA cluster
    const __bf16* BsC = &Bs[cur][0];
    const __bf16* AsC = &As[t & 1][0];
#pragma unroll
    for (int k2 = 0; k2 < 2; ++k2) {
      bf16x8 af[2], bfr[2];
#pragma unroll
      for (int mt = 0; mt < 2; ++mt)
        af[mt] = *reinterpret_cast<const bf16x8*>(&AsC[(mt * 16 + c) * 72 + k2 * 32 + q8]);
#pragma unroll
      for (int nt = 0; nt < 2; ++nt) {
        const int n = nsub + nt * 16 + c;
        const int s = ((k2 << 2) + q) ^ c7;      // un-swizzle on read
        bfr[nt] = *reinterpret_cast<const bf16x8*>(&BsC[n * 64 + (s << 3)]);
      }
#pragma unroll
      for (int mt = 0; mt < 2; ++mt)
#pragma unroll
        for (int nt = 0; nt < 2; ++nt)
          acc[mt][nt] = __builtin_amdgcn_mfma_f32_16x16x32_bf16(af[mt], bfr[nt],
                                                                acc[mt][nt], 0, 0, 0);
    }
    if (t <= 30) {
      if (t <= 29)
        asm volatile("s_waitcnt vmcnt(6)" ::: "memory");   // tile t+1 landed
      else
        asm volatile("s_waitcnt vmcnt(0)" ::: "memory");   // tail drain
      __builtin_amdgcn_sched_barrier(0);
      store_adj(pa_s, (t + 1) & 1);
      asm volatile("s_waitcnt lgkmcnt(0)" ::: "memory");
      __builtin_amdgcn_sched_barrier(0);
      __builtin_amdgcn_s_barrier();
    }
  };

  for (int t2 = 0; t2 < 32; t2 += 2) {
    body(t2, paA, paB);       // even t: issue tile t+2 into paA, store t+1 from paB
    body(t2 + 1, paB, paA);
  }

  // ---- Epilogue: out = y @ W + bias ----
  __syncthreads();                       // all k-loop LDS reads retired

  __bf16* yl = &As[0][0];                // y_lds [32 m][136 f]
  __bf16* WT = &Bs[0][0];                // WT    [128 j][136 f]

  // scatter y (fp32 acc) -> bf16 LDS; lane holds y[m=mt*16+q*4+r][f=nsub+nt*16+c]
#pragma unroll
  for (int mt = 0; mt < 2; ++mt)
#pragma unroll
    for (int nt = 0; nt < 2; ++nt)
#pragma unroll
      for (int r = 0; r < 4; ++r)
        yl[(mt * 16 + q * 4 + r) * 136 + nsub + nt * 16 + c] = f2bf(acc[mt][nt][r]);

  // stage WT[j][f] = bf16(W[f][j]); lanes vary j -> coalesced W reads
  {
    const int j = tid & 127;
    const int fh = (tid >> 7) << 6;      // 0 or 64
#pragma unroll
    for (int p = 0; p < 8; ++p) {
      const int f0 = fh + p * 8;
      bf16x8 v;
#pragma unroll
      for (int e = 0; e < 8; ++e)
        v[e] = f2bf(W[(size_t)(f0 + e) * F_DIM + j]);
      *reinterpret_cast<bf16x8*>(&WT[j * 136 + f0]) = v;
    }
  }
  __syncthreads();

  // per-wave: out[m 0..31][j in wave's 32-slice] = y(32x128) @ W(128x32)
  f32x4 acc2[2][2] = {};
#pragma unroll
  for (int k4 = 0; k4 < 4; ++k4) {
    const int kq = k4 * 32 + q8;
    bf16x8 ay[2], bw[2];
#pragma unroll
    for (int mt = 0; mt < 2; ++mt)
      ay[mt] = *reinterpret_cast<const bf16x8*>(&yl[(mt * 16 + c) * 136 + kq]);
#pragma unroll
    for (int jt = 0; jt < 2; ++jt)
      bw[jt] = *reinterpret_cast<const bf16x8*>(&WT[(nsub + jt * 16 + c) * 136 + kq]);
#pragma unroll
    for (int mt = 0; mt < 2; ++mt)
#pragma unroll
      for (int jt = 0; jt < 2; ++jt)
        acc2[mt][jt] = __builtin_amdgcn_mfma_f32_16x16x32_bf16(ay[mt], bw[jt],
                                                               acc2[mt][jt], 0, 0, 0);
  }

  float bv[2];
#pragma unroll
  for (int jt = 0; jt < 2; ++jt) bv[jt] = bias[nsub + jt * 16 + c];
#pragma unroll
  for (int mt = 0; mt < 2; ++mt)
#pragma unroll
    for (int jt = 0; jt < 2; ++jt)
#pragma unroll
      for (int r = 0; r < 4; ++r) {
        int m = m0 + mt * 16 + q * 4 + r;
        int j = nsub + jt * 16 + c;
        __builtin_nontemporal_store(acc2[mt][jt][r] + bv[jt],
                                    &out[((size_t)b * N_DIM + m) * F_DIM + j]);
      }
}

extern "C" void kernel_launch(void* const* d_in, const int* in_sizes, int n_in,
                              void* d_out, int out_size, void* d_ws, size_t ws_size,
                              hipStream_t stream) {
  const float* x    = (const float*)d_in[0];
  const float* adj  = (const float*)d_in[1];
  const float* W    = (const float*)d_in[2];
  const float* bias = (const float*)d_in[3];
  float* out = (float*)d_out;
  __bf16* xT = (__bf16*)d_ws;   // 8*128*2048*2 = 4 MB scratch

  gcn_xt<<<B_DIM * 32, 256, 0, stream>>>(x, xT);
  gcn_fused<<<B_DIM * 64, 256, 0, stream>>>(adj, xT, W, bias, out);
}